// Round 5
// baseline (976.295 us; speedup 1.0000x reference)
//
#include <hip/hip_runtime.h>
#include <stdint.h>

typedef short bf16x8 __attribute__((ext_vector_type(8)));
typedef float f32x4 __attribute__((ext_vector_type(4)));

#define NEG (-10000.0f)
#define LOG2E 1.44269504089f
#define LN2 0.69314718056f
#define EXP2F(x) __builtin_amdgcn_exp2f(x)
#define LOG2F(x) __builtin_amdgcn_logf(x)
#define RCPF(x) __builtin_amdgcn_rcpf(x)
constexpr int T_LEN = 512;
constexpr int BATCH = 128;

__device__ __forceinline__ unsigned short f2bf(float f) {
    union { float f; unsigned u; } v; v.f = f;
    return (unsigned short)((v.u + 0x7FFFu + ((v.u >> 16) & 1u)) >> 16);
}

__device__ __forceinline__ f32x4 mfma16(bf16x8 a, bf16x8 b, f32x4 c) {
    return __builtin_amdgcn_mfma_f32_16x16x32_bf16(a, b, c, 0, 0, 0);
}

// ---------------- 1) embedding gather + bf16 convert: xt[b][t][64] ----------------
__global__ void __launch_bounds__(256) k_embed(const int* __restrict__ sent,
                                               const float* __restrict__ emb,
                                               unsigned short* __restrict__ xt) {
    int gid = blockIdx.x * 256 + threadIdx.x;
    int row = gid >> 5;                            // b*T + t
    int p   = gid & 31;
    int w = sent[row];
    float2 v = *(const float2*)(emb + (size_t)w * 64 + p * 2);
    unsigned o = (unsigned)f2bf(v.x) | ((unsigned)f2bf(v.y) << 16);
    ((unsigned*)xt)[(size_t)row * 32 + p] = o;
}

// ---------------- 2) BiLSTM v2: 16 chains per block in MFMA M-rows ----------------
// 16 blocks (8 fwd + 8 bwd) x 512 threads (8 waves). Block owns 16 batch chains of
// one direction. Wave w owns units [16w,16w+16) x all 4 gates x all 16 chains:
//   A (16x32 k-slice) = S[chain][k]  (chains ride the M dimension, NO M-waste)
//   B frags = weights, PRESCALED by -log2e (i,f,o) / -2log2e (g) so each
//   sigmoid/tanh needs only exp2+add+rcp. Bias folded into acc init.
// C-layout: row=chain=4*kg+r, col=unit=16w+nlo -> gate math fully in-register,
// 4 chains per lane (c[4] state). h exchange: 4x ds_write_b16 -> barrier ->
// 4x ds_read_b128, layout hl[chain][unit] stride 132 (2-way banks = free).
// x: global->register A-frags, distance-2 prefetch via unroll-by-2.
__global__ void __launch_bounds__(512, 2) k_lstm(
        const unsigned short* __restrict__ xt,     // (B,T,64) bf16
        const float* __restrict__ Wih_f, const float* __restrict__ Whh_f, const float* __restrict__ b_f,
        const float* __restrict__ Wih_b, const float* __restrict__ Whh_b, const float* __restrict__ b_b,
        unsigned short* __restrict__ hbuf) {       // (B,T,256) bf16: [h_f | h_b]
    const int tid  = threadIdx.x;
    const int lane = tid & 63;
    const int w    = tid >> 6;            // wave 0..7: unit slice [16w,16w+16)
    const int dir  = blockIdx.x >> 3;
    const int b0   = (blockIdx.x & 7) * 16;

    const float* Wih  = dir ? Wih_b : Wih_f;
    const float* Whh  = dir ? Whh_b : Whh_f;
    const float* bias = dir ? b_b   : b_f;

    __shared__ __align__(16) unsigned short hl[2 * 16 * 132];   // [pp][chain][unit(pad)]

    const int nlo  = lane & 15;
    const int kg   = lane >> 4;
    const int unit = 16 * w + nlo;

    // ---- B fragments: 6 k-tiles x 4 gates, prescaled weights resident in VGPRs ----
    bf16x8 bfrag[6][4];
    float bsc[4];
    #pragma unroll
    for (int g = 0; g < 4; ++g) {
        const float sc = (g == 2) ? (-2.0f * LOG2E) : (-LOG2E);
        const int j = 128 * g + unit;
        bsc[g] = bias[j] * sc;
        #pragma unroll
        for (int kt = 0; kt < 6; ++kt) {
            const float* src = (kt < 2) ? (Wih + (size_t)j * 64  + 32 * kt       + kg * 8)
                                        : (Whh + (size_t)j * 128 + 32 * (kt - 2) + kg * 8);
            bf16x8 tmp;
            #pragma unroll
            for (int q = 0; q < 8; ++q) tmp[q] = (short)f2bf(src[q] * sc);
            bfrag[kt][g] = tmp;
        }
    }

    for (int i = tid; i < 2 * 16 * 132; i += 512) hl[i] = 0;
    __syncthreads();

    float c[4] = {0.f, 0.f, 0.f, 0.f};      // cell state, chains 4*kg+r
    const unsigned short* xrow = xt + (size_t)(b0 + nlo) * T_LEN * 64 + kg * 8;
    unsigned short* hb = hbuf + ((size_t)(b0 + 4 * kg) * T_LEN) * 256 + dir * 128 + unit;

    const int te = dir ? 511 : 0, to = dir ? 510 : 1;
    bf16x8 xe0 = *(const bf16x8*)(xrow + te * 64);
    bf16x8 xe1 = *(const bf16x8*)(xrow + te * 64 + 32);
    bf16x8 xo0 = *(const bf16x8*)(xrow + to * 64);
    bf16x8 xo1 = *(const bf16x8*)(xrow + to * 64 + 32);

    auto do_step = [&](int t, int p, bf16x8 ax0, bf16x8 ax1) {
        const unsigned short* hr = hl + p * 2112 + nlo * 132 + kg * 8;
        bf16x8 h0 = *(const bf16x8*)(hr);
        bf16x8 h1 = *(const bf16x8*)(hr + 32);
        bf16x8 h2 = *(const bf16x8*)(hr + 64);
        bf16x8 h3 = *(const bf16x8*)(hr + 96);

        f32x4 acc[4];
        #pragma unroll
        for (int g = 0; g < 4; ++g) {
            f32x4 a = (f32x4){bsc[g], bsc[g], bsc[g], bsc[g]};
            a = mfma16(ax0, bfrag[0][g], a);
            a = mfma16(ax1, bfrag[1][g], a);
            a = mfma16(h0,  bfrag[2][g], a);
            a = mfma16(h1,  bfrag[3][g], a);
            a = mfma16(h2,  bfrag[4][g], a);
            a = mfma16(h3,  bfrag[5][g], a);
            acc[g] = a;
        }

        unsigned short* hw = hl + (1 - p) * 2112 + unit;
        #pragma unroll
        for (int r = 0; r < 4; ++r) {
            float ig = RCPF(1.0f + EXP2F(acc[0][r]));          // acc = -log2e*z
            float fg = RCPF(1.0f + EXP2F(acc[1][r]));
            float tg = 2.0f * RCPF(1.0f + EXP2F(acc[2][r])) - 1.0f;   // acc = -2log2e*z
            float og = RCPF(1.0f + EXP2F(acc[3][r]));
            c[r] = fg * c[r] + ig * tg;
            float tc = 2.0f * RCPF(1.0f + EXP2F(-2.0f * LOG2E * c[r])) - 1.0f;
            unsigned short hv = f2bf(og * tc);
            hw[(4 * kg + r) * 132] = hv;                              // LDS for t+1
            hb[(size_t)r * T_LEN * 256 + (size_t)t * 256] = hv;       // fire-and-forget
        }

        // raw barrier: drain LDS ops only, not the global stores / x prefetch
        __asm__ volatile("" ::: "memory");
        __builtin_amdgcn_s_waitcnt(0xc07f);
        __builtin_amdgcn_s_barrier();
        __asm__ volatile("" ::: "memory");
    };

    for (int s = 0; s < T_LEN; s += 2) {
        const int tE = dir ? (511 - s) : s;
        do_step(tE, 0, xe0, xe1);
        int tp = dir ? (511 - (s + 2)) : (s + 2);
        tp = min(max(tp, 0), 511);
        xe0 = *(const bf16x8*)(xrow + tp * 64);
        xe1 = *(const bf16x8*)(xrow + tp * 64 + 32);

        const int tO = dir ? (511 - (s + 1)) : (s + 1);
        do_step(tO, 1, xo0, xo1);
        int tq = dir ? (511 - (s + 3)) : (s + 3);
        tq = min(max(tq, 0), 511);
        xo0 = *(const bf16x8*)(xrow + tq * 64);
        xo1 = *(const bf16x8*)(xrow + tq * 64 + 32);
    }
}

// ---------------- 3) feats = [h_f|h_b] @ W_out^T + b_out  (BT x 32) ----------------
__global__ void __launch_bounds__(256) k_feats(const unsigned short* __restrict__ hbuf,
                                               const float* __restrict__ Wout,
                                               const float* __restrict__ bout,
                                               float* __restrict__ feats) {
    const int lane = threadIdx.x & 63;
    const int wv   = blockIdx.x * 4 + (threadIdx.x >> 6);
    const int nlo  = lane & 15, kg = lane >> 4;

    bf16x8 bw[2][8];
    #pragma unroll
    for (int nt = 0; nt < 2; ++nt) {
        const float* src0 = Wout + (size_t)(nt * 16 + nlo) * 256 + kg * 8;
        #pragma unroll
        for (int kt = 0; kt < 8; ++kt) {
            bf16x8 tmp;
            #pragma unroll
            for (int q = 0; q < 8; ++q) tmp[q] = (short)f2bf(src0[kt * 32 + q]);
            bw[nt][kt] = tmp;
        }
    }
    float bb0 = bout[nlo], bb1 = bout[16 + nlo];

    for (int rg = 0; rg < 4; ++rg) {
        int row0 = wv * 64 + rg * 16;
        f32x4 a0 = {0.f,0.f,0.f,0.f}, a1 = {0.f,0.f,0.f,0.f};
        #pragma unroll
        for (int kt = 0; kt < 8; ++kt) {
            bf16x8 a = *(const bf16x8*)(hbuf + (size_t)(row0 + nlo) * 256 + kt * 32 + kg * 8);
            a0 = mfma16(a, bw[0][kt], a0);
            a1 = mfma16(a, bw[1][kt], a1);
        }
        #pragma unroll
        for (int r = 0; r < 4; ++r) {
            size_t rr = (size_t)(row0 + kg * 4 + r) * 32;
            feats[rr + nlo]      = a0[r] + bb0;
            feats[rr + 16 + nlo] = a1[r] + bb1;
        }
    }
}

// ---------------- 4) CRF forward + gold: one wave per batch, fv in registers ----------------
__global__ void __launch_bounds__(64) k_crf(const float* __restrict__ feats,
                                            const float* __restrict__ trans,
                                            const int* __restrict__ tags,
                                            float* __restrict__ out) {
    const int b    = blockIdx.x;
    const int lane = threadIdx.x;
    const int k1   = lane & 31;
    const int half = lane >> 5;

    __shared__ float str[1024];
    for (int i = lane; i < 1024; i += 64) str[i] = trans[i];

    float tr2[16];
    #pragma unroll
    for (int j = 0; j < 16; ++j) tr2[j] = trans[k1 * 32 + half * 16 + j] * LOG2E;
    __syncthreads();

    // gold score
    const int* tg = tags + (size_t)b * T_LEN;
    const float* fb = feats + (size_t)b * T_LEN * 32;
    float gsum = 0.0f;
    for (int t = lane; t < T_LEN; t += 64) {
        int cur = tg[t];
        int prev = t ? tg[t - 1] : 0;
        gsum += str[cur * 32 + prev] + fb[(size_t)t * 32 + cur];
    }
    #pragma unroll
    for (int o = 32; o >= 1; o >>= 1) gsum += __shfl_xor(gsum, o);

    // forward recurrence (log2 domain, register fv, shuffle gather, common stale offset)
    float fv2  = (k1 == 0) ? 0.0f : NEG * LOG2E;
    float coff = NEG * LOG2E;
    float ev2  = fb[k1] * LOG2E;

    for (int t = 0; t < T_LEN; ++t) {
        float evn = (t + 1 < T_LEN) ? fb[(size_t)(t + 1) * 32 + k1] : 0.0f;
        float trc[16];
        #pragma unroll
        for (int j = 0; j < 16; ++j) trc[j] = tr2[j] - coff;
        float p0 = 0.f, p1 = 0.f, p2 = 0.f, p3 = 0.f;
        #pragma unroll
        for (int j = 0; j < 16; j += 4) {
            float f0 = __shfl(fv2, half * 16 + j);
            float f1 = __shfl(fv2, half * 16 + j + 1);
            float f2 = __shfl(fv2, half * 16 + j + 2);
            float f3 = __shfl(fv2, half * 16 + j + 3);
            p0 += EXP2F(f0 + trc[j]);
            p1 += EXP2F(f1 + trc[j + 1]);
            p2 += EXP2F(f2 + trc[j + 2]);
            p3 += EXP2F(f3 + trc[j + 3]);
        }
        float p = (p0 + p1) + (p2 + p3);
        p += __shfl_xor(p, 32);
        p = fmaxf(p, 1e-37f);              // lane-0 underflow guard
        fv2  = coff + LOG2F(p) + ev2;
        coff = __shfl(fv2, 16);            // common offset: bulk lane's level
        ev2  = evn * LOG2E;
    }

    float v2 = fv2 + str[k1] * LOG2E;
    float m2 = v2;
    #pragma unroll
    for (int o = 32; o >= 1; o >>= 1) m2 = fmaxf(m2, __shfl_xor(m2, o));
    float e = EXP2F(v2 - m2);
    #pragma unroll
    for (int o = 32; o >= 1; o >>= 1) e += __shfl_xor(e, o);
    float logZ = LN2 * (m2 + LOG2F(e) - 1.0f);   // -1: each k counted twice

    if (lane == 0) {
        float gold = gsum + str[tg[T_LEN - 1]];
        atomicAdd(out, logZ - gold);
    }
}

extern "C" void kernel_launch(void* const* d_in, const int* in_sizes, int n_in,
                              void* d_out, int out_size, void* d_ws, size_t ws_size,
                              hipStream_t stream) {
    const int*   sent  = (const int*)d_in[0];
    const int*   tags  = (const int*)d_in[1];
    const float* emb   = (const float*)d_in[2];
    const float* Wih_f = (const float*)d_in[3];
    const float* Whh_f = (const float*)d_in[4];
    const float* b_f   = (const float*)d_in[5];
    const float* Wih_b = (const float*)d_in[6];
    const float* Whh_b = (const float*)d_in[7];
    const float* b_b   = (const float*)d_in[8];
    const float* Wout  = (const float*)d_in[9];
    const float* bout  = (const float*)d_in[10];
    const float* trans = (const float*)d_in[11];
    (void)in_sizes; (void)n_in; (void)ws_size;

    char* ws = (char*)d_ws;
    unsigned short* hbuf  = (unsigned short*)ws;                         // 33,554,432 B
    float*          feats = (float*)(ws + 33554432);                     //  8,388,608 B
    unsigned short* xt    = (unsigned short*)(ws + 33554432 + 8388608);  //  8,388,608 B

    (void)hipMemsetAsync(d_out, 0, sizeof(float) * out_size, stream);
    k_embed<<<8192, 256, 0, stream>>>(sent, emb, xt);
    k_lstm <<<16,   512, 0, stream>>>(xt, Wih_f, Whh_f, b_f, Wih_b, Whh_b, b_b, hbuf);
    k_feats<<<256,  256, 0, stream>>>(hbuf, Wout, bout, feats);
    k_crf  <<<BATCH, 64, 0, stream>>>(feats, trans, tags, (float*)d_out);
}

// Round 6
// 556.919 us; speedup vs baseline: 1.7530x; 1.7530x over previous
//
#include <hip/hip_runtime.h>
#include <stdint.h>

typedef short bf16x8 __attribute__((ext_vector_type(8)));
typedef float f32x4 __attribute__((ext_vector_type(4)));

#define NEG (-10000.0f)
#define LOG2E 1.44269504089f
#define LN2 0.69314718056f
#define EXP2F(x) __builtin_amdgcn_exp2f(x)
#define LOG2F(x) __builtin_amdgcn_logf(x)
#define RCPF(x) __builtin_amdgcn_rcpf(x)
constexpr int T_LEN = 512;
constexpr int BATCH = 128;

__device__ __forceinline__ unsigned short f2bf(float f) {
    union { float f; unsigned u; } v; v.f = f;
    return (unsigned short)((v.u + 0x7FFFu + ((v.u >> 16) & 1u)) >> 16);
}
__device__ __forceinline__ float bf2f(unsigned short s) {
    union { unsigned u; float f; } v; v.u = (unsigned)s << 16; return v.f;
}
__device__ __forceinline__ f32x4 mfma16(bf16x8 a, bf16x8 b, f32x4 c) {
    return __builtin_amdgcn_mfma_f32_16x16x32_bf16(a, b, c, 0, 0, 0);
}

// ---------------- 1) embedding gather + bf16 convert: xt[b][t][64] ----------------
__global__ void __launch_bounds__(256) k_embed(const int* __restrict__ sent,
                                               const float* __restrict__ emb,
                                               unsigned short* __restrict__ xt) {
    int gid = blockIdx.x * 256 + threadIdx.x;
    int row = gid >> 5;                            // b*T + t
    int p   = gid & 31;
    int w = sent[row];
    float2 v = *(const float2*)(emb + (size_t)w * 64 + p * 2);
    unsigned o = (unsigned)f2bf(v.x) | ((unsigned)f2bf(v.y) << 16);
    ((unsigned*)xt)[(size_t)row * 32 + p] = o;
}

// ---------------- 2) BiLSTM v3: 1 chain/block; x@Wih chunked into LDS ----------------
// 256 blocks (b,dir) x 8 waves. Every 32 steps all waves densely compute
// zx = sc*(Wih·x + b) for the NEXT 32 timesteps (timesteps ride M: 16 MFMA/wave,
// amortized 0.5/step) into a double-buffered LDS tile zbuf[2][32][u*4+g] (bf16).
// The serial loop keeps only the h-dependent work: 1 ds_read_b64 (4 gates zx),
// 4 broadcast ds_read_b128 (h), 16 MFMA (Whh, prescaled by -log2e/-2log2e),
// exp2-only gate math, 1 LDS + 1 global h-write, raw lgkm-only barrier.
__global__ void __launch_bounds__(512, 2) k_lstm(
        const unsigned short* __restrict__ xt,     // (B,T,64) bf16
        const float* __restrict__ Wih_f, const float* __restrict__ Whh_f, const float* __restrict__ b_f,
        const float* __restrict__ Wih_b, const float* __restrict__ Whh_b, const float* __restrict__ b_b,
        unsigned short* __restrict__ hbuf) {       // (B,T,256) bf16: [h_f | h_b]
    const int tid  = threadIdx.x;
    const int lane = tid & 63;
    const int w    = tid >> 6;            // wave 0..7: unit slice [16w,16w+16)
    const int b    = blockIdx.x & 127;
    const int dir  = blockIdx.x >> 7;

    const float* Wih  = dir ? Wih_b : Wih_f;
    const float* Whh  = dir ? Whh_b : Whh_f;
    const float* bias = dir ? b_b   : b_f;

    __shared__ __align__(16) unsigned short zbuf[2][32][512];  // [buf][t][u*4+g] 64KB
    __shared__ __align__(16) unsigned short hl[2][128];        // h ping-pong

    const int nlo = lane & 15;
    const int kg  = lane >> 4;
    const int u   = 16 * w + nlo;         // hidden unit owned by this lane

    // ---- Whh B-frags: 4 gates x 4 k-tiles, prescaled, resident ----
    bf16x8 hfrag[4][4];
    #pragma unroll
    for (int g = 0; g < 4; ++g) {
        const float sc = (g == 2) ? (-2.0f * LOG2E) : (-LOG2E);
        const int j = 128 * g + u;
        #pragma unroll
        for (int kt = 0; kt < 4; ++kt) {
            const float* src = Whh + (size_t)j * 128 + 32 * kt + kg * 8;
            bf16x8 tmp;
            #pragma unroll
            for (int q = 0; q < 8; ++q) tmp[q] = (short)f2bf(src[q] * sc);
            hfrag[g][kt] = tmp;
        }
    }
    // ---- Wih B-frags for zx phase: wave's n-span [64w,64w+64): 4 n-tiles x 2 k ----
    bf16x8 wx[4][2];
    float bsc[4];
    #pragma unroll
    for (int nt = 0; nt < 4; ++nt) {
        const int n = 64 * w + 16 * nt + nlo;
        const float scn = ((n >> 7) == 2) ? (-2.0f * LOG2E) : (-LOG2E);
        bsc[nt] = bias[n] * scn;
        #pragma unroll
        for (int kt = 0; kt < 2; ++kt) {
            const float* src = Wih + (size_t)n * 64 + 32 * kt + kg * 8;
            bf16x8 tmp;
            #pragma unroll
            for (int q = 0; q < 8; ++q) tmp[q] = (short)f2bf(src[q] * scn);
            wx[nt][kt] = tmp;
        }
    }

    const unsigned short* xb = xt + (size_t)b * T_LEN * 64;

    // x A-frags for chunk c: rows m=16rt+nlo <-> step 32c+m (time-reversed if dir)
    auto load_x = [&](int c, bf16x8 xf[2][2]) {
        const int tb = dir ? (511 - 32 * c) : (32 * c);
        #pragma unroll
        for (int rt = 0; rt < 2; ++rt) {
            const int m = 16 * rt + nlo;
            const int t = dir ? (tb - m) : (tb + m);
            xf[rt][0] = *(const bf16x8*)(xb + t * 64 + kg * 8);
            xf[rt][1] = *(const bf16x8*)(xb + t * 64 + 32 + kg * 8);
        }
    };
    // dense zx burst: 16 MFMA/wave covering 32 steps x 64 n-cols
    auto zx_phase = [&](int buf, bf16x8 xf[2][2]) {
        #pragma unroll
        for (int rt = 0; rt < 2; ++rt) {
            #pragma unroll
            for (int nt = 0; nt < 4; ++nt) {
                f32x4 a = (f32x4){bsc[nt], bsc[nt], bsc[nt], bsc[nt]};
                a = mfma16(xf[rt][0], wx[nt][0], a);
                a = mfma16(xf[rt][1], wx[nt][1], a);
                const int n = 64 * w + 16 * nt + nlo;
                const int base = (n & 127) * 4 + (n >> 7);   // [u*4+g] packing
                #pragma unroll
                for (int r = 0; r < 4; ++r)
                    zbuf[buf][16 * rt + 4 * kg + r][base] = f2bf(a[r]);
            }
        }
    };

    if (tid < 128) { hl[0][tid] = 0; hl[1][tid] = 0; }
    bf16x8 xfA[2][2], xfB[2][2];
    load_x(0, xfA);
    zx_phase(0, xfA);
    load_x(1, xfB);
    __syncthreads();

    float c = 0.0f;                        // cell state (kg-redundant, lockstep)
    unsigned short* hb = hbuf + ((size_t)b * T_LEN) * 256 + dir * 128 + u;

    for (int ch = 0; ch < 16; ++ch) {
        const int p = ch & 1;
        if (ch + 1 < 16) zx_phase(1 - p, p ? xfA : xfB);   // next chunk's zx
        if (ch + 2 < 16) load_x(ch + 2, p ? xfB : xfA);    // prefetch chunk+2 x

        for (int s = 0; s < 32; ++s) {
            const int gs = 32 * ch + s;
            const int hp = gs & 1;

            ushort4 zv = *(const ushort4*)(&zbuf[p][s][u * 4]);   // 4 gates' zx
            const unsigned short* hr = hl[hp];
            bf16x8 h0 = *(const bf16x8*)(hr      + kg * 8);
            bf16x8 h1 = *(const bf16x8*)(hr + 32 + kg * 8);
            bf16x8 h2 = *(const bf16x8*)(hr + 64 + kg * 8);
            bf16x8 h3 = *(const bf16x8*)(hr + 96 + kg * 8);

            float zi = bf2f(zv.x), zf = bf2f(zv.y), zg = bf2f(zv.z), zo = bf2f(zv.w);
            f32x4 ai = (f32x4){zi, zi, zi, zi};
            f32x4 af = (f32x4){zf, zf, zf, zf};
            f32x4 ag = (f32x4){zg, zg, zg, zg};
            f32x4 ao = (f32x4){zo, zo, zo, zo};
            #pragma unroll
            for (int kt = 0; kt < 4; ++kt) {
                bf16x8 hh = (kt == 0) ? h0 : (kt == 1) ? h1 : (kt == 2) ? h2 : h3;
                ai = mfma16(hh, hfrag[0][kt], ai);
                af = mfma16(hh, hfrag[1][kt], af);
                ag = mfma16(hh, hfrag[2][kt], ag);
                ao = mfma16(hh, hfrag[3][kt], ao);
            }

            float ig = RCPF(1.0f + EXP2F(ai[0]));              // acc = -log2e*z
            float fg = RCPF(1.0f + EXP2F(af[0]));
            float tg = 2.0f * RCPF(1.0f + EXP2F(ag[0])) - 1.0f; // acc = -2log2e*z
            float og = RCPF(1.0f + EXP2F(ao[0]));
            c = fg * c + ig * tg;
            float tc = 2.0f * RCPF(1.0f + EXP2F(-2.0f * LOG2E * c)) - 1.0f;
            unsigned short hv = f2bf(og * tc);

            if (kg == 0) {
                hl[1 - hp][u] = hv;                            // next step's A operand
                const int t_src = dir ? (511 - gs) : gs;
                hb[(size_t)t_src * 256] = hv;                  // fire-and-forget
            }
            // raw barrier: drain LDS ops only, not global stores / x prefetch
            __asm__ volatile("" ::: "memory");
            __builtin_amdgcn_s_waitcnt(0xc07f);
            __builtin_amdgcn_s_barrier();
            __asm__ volatile("" ::: "memory");
        }
    }
}

// ---------------- 3) feats = [h_f|h_b] @ W_out^T + b_out  (BT x 32) ----------------
__global__ void __launch_bounds__(256) k_feats(const unsigned short* __restrict__ hbuf,
                                               const float* __restrict__ Wout,
                                               const float* __restrict__ bout,
                                               float* __restrict__ feats) {
    const int lane = threadIdx.x & 63;
    const int wv   = blockIdx.x * 4 + (threadIdx.x >> 6);
    const int nlo  = lane & 15, kg = lane >> 4;

    bf16x8 bw[2][8];
    #pragma unroll
    for (int nt = 0; nt < 2; ++nt) {
        const float* src0 = Wout + (size_t)(nt * 16 + nlo) * 256 + kg * 8;
        #pragma unroll
        for (int kt = 0; kt < 8; ++kt) {
            bf16x8 tmp;
            #pragma unroll
            for (int q = 0; q < 8; ++q) tmp[q] = (short)f2bf(src0[kt * 32 + q]);
            bw[nt][kt] = tmp;
        }
    }
    float bb0 = bout[nlo], bb1 = bout[16 + nlo];

    for (int rg = 0; rg < 4; ++rg) {
        int row0 = wv * 64 + rg * 16;
        f32x4 a0 = {0.f,0.f,0.f,0.f}, a1 = {0.f,0.f,0.f,0.f};
        #pragma unroll
        for (int kt = 0; kt < 8; ++kt) {
            bf16x8 a = *(const bf16x8*)(hbuf + (size_t)(row0 + nlo) * 256 + kt * 32 + kg * 8);
            a0 = mfma16(a, bw[0][kt], a0);
            a1 = mfma16(a, bw[1][kt], a1);
        }
        #pragma unroll
        for (int r = 0; r < 4; ++r) {
            size_t rr = (size_t)(row0 + kg * 4 + r) * 32;
            feats[rr + nlo]      = a0[r] + bb0;
            feats[rr + 16 + nlo] = a1[r] + bb1;
        }
    }
}

// ---------------- 4) CRF forward + gold: one wave per batch, fv in registers ----------------
__global__ void __launch_bounds__(64) k_crf(const float* __restrict__ feats,
                                            const float* __restrict__ trans,
                                            const int* __restrict__ tags,
                                            float* __restrict__ out) {
    const int b    = blockIdx.x;
    const int lane = threadIdx.x;
    const int k1   = lane & 31;
    const int half = lane >> 5;

    __shared__ float str[1024];
    for (int i = lane; i < 1024; i += 64) str[i] = trans[i];

    float tr2[16];
    #pragma unroll
    for (int j = 0; j < 16; ++j) tr2[j] = trans[k1 * 32 + half * 16 + j] * LOG2E;
    __syncthreads();

    // gold score
    const int* tg = tags + (size_t)b * T_LEN;
    const float* fb = feats + (size_t)b * T_LEN * 32;
    float gsum = 0.0f;
    for (int t = lane; t < T_LEN; t += 64) {
        int cur = tg[t];
        int prev = t ? tg[t - 1] : 0;
        gsum += str[cur * 32 + prev] + fb[(size_t)t * 32 + cur];
    }
    #pragma unroll
    for (int o = 32; o >= 1; o >>= 1) gsum += __shfl_xor(gsum, o);

    // forward recurrence (log2 domain, register fv, shuffle gather, common stale offset)
    float fv2  = (k1 == 0) ? 0.0f : NEG * LOG2E;
    float coff = NEG * LOG2E;
    float ev2  = fb[k1] * LOG2E;

    for (int t = 0; t < T_LEN; ++t) {
        float evn = (t + 1 < T_LEN) ? fb[(size_t)(t + 1) * 32 + k1] : 0.0f;
        float trc[16];
        #pragma unroll
        for (int j = 0; j < 16; ++j) trc[j] = tr2[j] - coff;
        float p0 = 0.f, p1 = 0.f, p2 = 0.f, p3 = 0.f;
        #pragma unroll
        for (int j = 0; j < 16; j += 4) {
            float f0 = __shfl(fv2, half * 16 + j);
            float f1 = __shfl(fv2, half * 16 + j + 1);
            float f2 = __shfl(fv2, half * 16 + j + 2);
            float f3 = __shfl(fv2, half * 16 + j + 3);
            p0 += EXP2F(f0 + trc[j]);
            p1 += EXP2F(f1 + trc[j + 1]);
            p2 += EXP2F(f2 + trc[j + 2]);
            p3 += EXP2F(f3 + trc[j + 3]);
        }
        float p = (p0 + p1) + (p2 + p3);
        p += __shfl_xor(p, 32);
        p = fmaxf(p, 1e-37f);              // lane-0 underflow guard
        fv2  = coff + LOG2F(p) + ev2;
        coff = __shfl(fv2, 16);            // common offset: bulk lane's level
        ev2  = evn * LOG2E;
    }

    float v2 = fv2 + str[k1] * LOG2E;
    float m2 = v2;
    #pragma unroll
    for (int o = 32; o >= 1; o >>= 1) m2 = fmaxf(m2, __shfl_xor(m2, o));
    float e = EXP2F(v2 - m2);
    #pragma unroll
    for (int o = 32; o >= 1; o >>= 1) e += __shfl_xor(e, o);
    float logZ = LN2 * (m2 + LOG2F(e) - 1.0f);   // -1: each k counted twice

    if (lane == 0) {
        float gold = gsum + str[tg[T_LEN - 1]];
        atomicAdd(out, logZ - gold);
    }
}

extern "C" void kernel_launch(void* const* d_in, const int* in_sizes, int n_in,
                              void* d_out, int out_size, void* d_ws, size_t ws_size,
                              hipStream_t stream) {
    const int*   sent  = (const int*)d_in[0];
    const int*   tags  = (const int*)d_in[1];
    const float* emb   = (const float*)d_in[2];
    const float* Wih_f = (const float*)d_in[3];
    const float* Whh_f = (const float*)d_in[4];
    const float* b_f   = (const float*)d_in[5];
    const float* Wih_b = (const float*)d_in[6];
    const float* Whh_b = (const float*)d_in[7];
    const float* b_b   = (const float*)d_in[8];
    const float* Wout  = (const float*)d_in[9];
    const float* bout  = (const float*)d_in[10];
    const float* trans = (const float*)d_in[11];
    (void)in_sizes; (void)n_in; (void)ws_size;

    char* ws = (char*)d_ws;
    unsigned short* hbuf  = (unsigned short*)ws;                         // 33,554,432 B
    float*          feats = (float*)(ws + 33554432);                     //  8,388,608 B
    unsigned short* xt    = (unsigned short*)(ws + 33554432 + 8388608);  //  8,388,608 B

    (void)hipMemsetAsync(d_out, 0, sizeof(float) * out_size, stream);
    k_embed<<<8192, 256, 0, stream>>>(sent, emb, xt);
    k_lstm <<<256,  512, 0, stream>>>(xt, Wih_f, Whh_f, b_f, Wih_b, Whh_b, b_b, hbuf);
    k_feats<<<256,  256, 0, stream>>>(hbuf, Wout, bout, feats);
    k_crf  <<<BATCH, 64, 0, stream>>>(feats, trans, tags, (float*)d_out);
}